// Round 6
// baseline (261.504 us; speedup 1.0000x reference)
//
#include <hip/hip_runtime.h>
#include <math.h>

typedef __attribute__((ext_vector_type(8))) short short8;   // 8 bf16 (4 VGPRs)
typedef __attribute__((ext_vector_type(4))) float f32x4;    // MFMA accumulator

constexpr int kD  = 2048;
constexpr int kE  = 64;
constexpr int kM  = 16;          // tokens per block -> 1024 blocks -> 4/CU
constexpr int kGC = kD / 32;     // 64 k-chunks (K=32 per MFMA)

// p limbs pre-converted to MFMA B-fragment order, planes interleaved per chunk
// so each wave streams contiguous 3KB blocks:
// g_B[((e0*64 + gc)*3 + plane)*512 + L*8 + j],  L = 16*((k>>3)&3) + (e&15)
__device__ unsigned short g_B[4 * 64 * 3 * 512];   // 786 KB, L2-resident

// 3-limb truncated bf16 split: v = h + m + l + O(2^-24 |v|)
__device__ __forceinline__ void split3(float v, unsigned& h, unsigned& m, unsigned& l) {
  unsigned u = __float_as_uint(v);
  h = u & 0xFFFF0000u;
  float r1 = v - __uint_as_float(h);
  m = __float_as_uint(r1) & 0xFFFF0000u;
  float r2 = r1 - __uint_as_float(m);
  l = __float_as_uint(r2);
}

// pack limbs of two consecutive elements into one dword per plane
__device__ __forceinline__ void pack2(float e0, float e1,
                                      unsigned& dh, unsigned& dm, unsigned& dl) {
  unsigned h0, m0, l0, h1, m1, l1;
  split3(e0, h0, m0, l0);
  split3(e1, h1, m1, l1);
  dh = (h0 >> 16) | h1;
  dm = (m0 >> 16) | m1;
  dl = (l0 >> 16) | (l1 & 0xFFFF0000u);
}

union FragU { short8 s; unsigned u[4]; };

// ---------------------------------------------------------------------------
// Prep: S_e, inv_norm_e into ws; p 3-limb bf16 into g_B in B-fragment order.
// block e: thread t owns k in [8t, 8t+8) = one octet (gc = t>>2, o = t&3).
// ---------------------------------------------------------------------------
__global__ __launch_bounds__(256) void proto_prep(const float* __restrict__ p,
                                                  float* __restrict__ ws) {
  const int e = blockIdx.x, t = threadIdx.x;
  const float* row = p + (size_t)e * kD;
  float4 v0 = *(const float4*)(row + 8 * t);
  float4 v1 = *(const float4*)(row + 8 * t + 4);

  unsigned dh[4], dm[4], dl[4];
  pack2(v0.x, v0.y, dh[0], dm[0], dl[0]);
  pack2(v0.z, v0.w, dh[1], dm[1], dl[1]);
  pack2(v1.x, v1.y, dh[2], dm[2], dl[2]);
  pack2(v1.z, v1.w, dh[3], dm[3], dl[3]);
  const int gc = t >> 2, o = t & 3;
  const int Lr = 16 * o + (e & 15);
  size_t cb = (size_t)(((e >> 4) * 64 + gc) * 3) * 512 + Lr * 8;
  *(uint4*)&g_B[cb]          = make_uint4(dh[0], dh[1], dh[2], dh[3]);   // plane h
  *(uint4*)&g_B[cb + 512]    = make_uint4(dm[0], dm[1], dm[2], dm[3]);   // plane m
  *(uint4*)&g_B[cb + 1024]   = make_uint4(dl[0], dl[1], dl[2], dl[3]);   // plane l

  float s = (v0.x + v0.y) + (v0.z + v0.w) + (v1.x + v1.y) + (v1.z + v1.w);
  float q = v0.x*v0.x + v0.y*v0.y + v0.z*v0.z + v0.w*v0.w
          + v1.x*v1.x + v1.y*v1.y + v1.z*v1.z + v1.w*v1.w;
  #pragma unroll
  for (int off = 32; off >= 1; off >>= 1) {
    s += __shfl_xor(s, off, 64);
    q += __shfl_xor(q, off, 64);
  }
  __shared__ float as[4], aq[4];
  if ((t & 63) == 0) { as[t >> 6] = s; aq[t >> 6] = q; }
  __syncthreads();
  if (t == 0) {
    float S = (as[0] + as[1]) + (as[2] + as[3]);
    float Q = (aq[0] + aq[1]) + (aq[2] + aq[3]);
    ws[e]      = S;
    ws[kE + e] = 1.f / fmaxf(sqrtf(Q), 1e-8f);
  }
}

// ---------------------------------------------------------------------------
// Main: barrier-free streaming K-loop. Each wave: 16 tokens x 16 experts,
// full K. A-frags loaded DIRECTLY from global x in MFMA layout (32B/lane,
// full cache-line use), 3-limb packed in-register; B-frags from L2-hot g_B.
// Single __syncthreads before the top-2 epilogue.
// ---------------------------------------------------------------------------
__global__ __launch_bounds__(256, 4) void router_main(
    const float* __restrict__ x, const float* __restrict__ ws,
    float* __restrict__ out_w, float* __restrict__ out_i) {
  __shared__ float sLogit[kM * 68];   // 4352 B
  __shared__ float sStats[kM][2];     //  128 B

  const int t    = threadIdx.x;
  const int w    = t >> 6;          // wave: experts [16w, 16w+16)
  const int L    = t & 63;
  const int ln15 = L & 15;
  const int q    = L >> 4;
  const int tok0 = blockIdx.x * kM;

  // A-frag source: lane L -> token (L&15), k = gc*32 + q*8 + (0..7)
  const float* xa = x + (size_t)(tok0 + ln15) * kD + q * 8;
  // B-frag source: chunk stride 1536 ushorts (3 planes x 512)
  const unsigned short* bp = g_B + (size_t)w * (64 * 3 * 512) + L * 8;

  f32x4 acc = (f32x4){0.f, 0.f, 0.f, 0.f};
  float sx = 0.f, sxx = 0.f;

  // register pipeline: x depth-2, B depth-1
  float4 xv[2][2];
  short8 bv[3];
  xv[0][0] = *(const float4*)(xa);
  xv[0][1] = *(const float4*)(xa + 4);
  xv[1][0] = *(const float4*)(xa + 32);
  xv[1][1] = *(const float4*)(xa + 36);
  bv[0] = *(const short8*)(bp);
  bv[1] = *(const short8*)(bp + 512);
  bv[2] = *(const short8*)(bp + 1024);

  #pragma unroll 4
  for (int gc = 0; gc < kGC; ++gc) {
    float4 v0 = xv[gc & 1][0], v1 = xv[gc & 1][1];
    short8 bh = bv[0], bm = bv[1], bl = bv[2];
    if (gc + 1 < kGC) {                       // B prefetch, depth 1 (L2-hot)
      const unsigned short* nb = bp + (size_t)(gc + 1) * 1536;
      bv[0] = *(const short8*)(nb);
      bv[1] = *(const short8*)(nb + 512);
      bv[2] = *(const short8*)(nb + 1024);
    }
    if (gc + 2 < kGC) {                       // x prefetch, depth 2 (HBM)
      xv[gc & 1][0] = *(const float4*)(xa + (gc + 2) * 32);
      xv[gc & 1][1] = *(const float4*)(xa + (gc + 2) * 32 + 4);
    }
    // LN stats partials (this lane's token, its k-slice)
    sx += (v0.x + v0.y) + (v0.z + v0.w) + (v1.x + v1.y) + (v1.z + v1.w);
    sxx = fmaf(v0.x, v0.x, fmaf(v0.y, v0.y, fmaf(v0.z, v0.z, fmaf(v0.w, v0.w, sxx))));
    sxx = fmaf(v1.x, v1.x, fmaf(v1.y, v1.y, fmaf(v1.z, v1.z, fmaf(v1.w, v1.w, sxx))));
    // 3-limb A pack, in-register
    FragU ah, am, al;
    pack2(v0.x, v0.y, ah.u[0], am.u[0], al.u[0]);
    pack2(v0.z, v0.w, ah.u[1], am.u[1], al.u[1]);
    pack2(v1.x, v1.y, ah.u[2], am.u[2], al.u[2]);
    pack2(v1.z, v1.w, ah.u[3], am.u[3], al.u[3]);
    // 6 limb products: hh, hm, mh, mm, hl, lh (dropped terms <= 2^-24)
    acc = __builtin_amdgcn_mfma_f32_16x16x32_bf16(ah.s, bh, acc, 0, 0, 0);
    acc = __builtin_amdgcn_mfma_f32_16x16x32_bf16(ah.s, bm, acc, 0, 0, 0);
    acc = __builtin_amdgcn_mfma_f32_16x16x32_bf16(am.s, bh, acc, 0, 0, 0);
    acc = __builtin_amdgcn_mfma_f32_16x16x32_bf16(am.s, bm, acc, 0, 0, 0);
    acc = __builtin_amdgcn_mfma_f32_16x16x32_bf16(ah.s, bl, acc, 0, 0, 0);
    acc = __builtin_amdgcn_mfma_f32_16x16x32_bf16(al.s, bh, acc, 0, 0, 0);
  }

  // stats: lanes {L, L+16, L+32, L+48} share token (L&15) -> reduce over q
  sx  += __shfl_xor(sx, 16, 64);  sx  += __shfl_xor(sx, 32, 64);
  sxx += __shfl_xor(sxx, 16, 64); sxx += __shfl_xor(sxx, 32, 64);
  if (w == 0 && q == 0) {        // all waves compute identical stats; one writes
    sStats[ln15][0] = sx;
    sStats[ln15][1] = sxx;
  }

  // raw dot -> LDS  (C layout: row(token) = q*4+i, col(expert) = ln15)
  #pragma unroll
  for (int i = 0; i < 4; ++i)
    sLogit[(q * 4 + i) * 68 + w * 16 + ln15] = acc[i];
  __syncthreads();

  // epilogue: wave w -> tokens [4w, 4w+4), lane = expert
  const float Se  = ws[L];
  const float inv = ws[kE + L];
  #pragma unroll
  for (int tl = 0; tl < 4; ++tl) {
    int tk = w * 4 + tl;
    float mu   = sStats[tk][0] * (1.f / kD);
    float var  = sStats[tk][1] * (1.f / kD) - mu * mu;
    float rstd = rsqrtf(var + 1e-5f);
    float logit = (sLogit[tk * 68 + L] - mu * Se) * rstd * inv * 0.125f;

    float v1 = logit; int i1 = L;
    #pragma unroll
    for (int off = 32; off >= 1; off >>= 1) {
      float ov = __shfl_xor(v1, off, 64);
      int   oi = __shfl_xor(i1, off, 64);
      if (ov > v1 || (ov == v1 && oi < i1)) { v1 = ov; i1 = oi; }
    }
    float ml = (L == i1) ? -3.402823466e38f : logit;
    float v2 = ml; int i2 = L;
    #pragma unroll
    for (int off = 32; off >= 1; off >>= 1) {
      float ov = __shfl_xor(v2, off, 64);
      int   oi = __shfl_xor(i2, off, 64);
      if (ov > v2 || (ov == v2 && oi < i2)) { v2 = ov; i2 = oi; }
    }
    if (L == 0) {
      int tg = tok0 + tk;
      float er = expf(v2 - v1);
      float r  = 1.f / (1.f + er);
      out_w[2 * tg]     = r;
      out_w[2 * tg + 1] = er * r;
      out_i[2 * tg]     = (float)i1;   // harness reads whole buffer as f32
      out_i[2 * tg + 1] = (float)i2;
    }
  }
}

extern "C" void kernel_launch(void* const* d_in, const int* in_sizes, int n_in,
                              void* d_out, int out_size, void* d_ws, size_t ws_size,
                              hipStream_t stream) {
  const float* x = (const float*)d_in[0];   // [4,4096,2048] fp32
  const float* p = (const float*)d_in[1];   // [64,2048] fp32
  float* ws = (float*)d_ws;                 // 128 floats
  const int T = in_sizes[0] / kD;           // 16384 tokens
  float* out_w = (float*)d_out;
  float* out_i = (float*)d_out + (size_t)T * 2;

  proto_prep<<<kE, 256, 0, stream>>>(p, ws);
  router_main<<<T / kM, 256, 0, stream>>>(x, ws, out_w, out_i);
}

// Round 7
// 236.292 us; speedup vs baseline: 1.1067x; 1.1067x over previous
//
#include <hip/hip_runtime.h>
#include <math.h>

typedef __attribute__((ext_vector_type(8))) short short8;   // 8 bf16 (4 VGPRs)
typedef __attribute__((ext_vector_type(4))) float f32x4;    // MFMA accumulator

constexpr int kD   = 2048;
constexpr int kE   = 64;
constexpr int kTPW = 32;          // tokens per wave (= per 64-thread block)
constexpr int kGC  = kD / 32;     // 64 k-chunks (K=32 per MFMA)

// p limbs in MFMA B-fragment order, CHUNK-MAJOR so each wave streams g_B
// sequentially: g_B[((gc*4 + e0)*3 + plane)*512 + Lr*8 + j]
// Lr = 16*((k>>3)&3) + (e&15);  chunk block = 12 KB.
__device__ unsigned short g_B[64 * 4 * 3 * 512];   // 786 KB, L2-resident

// 3-limb truncated bf16 split: v = h + m + l + O(2^-24 |v|)
__device__ __forceinline__ void split3(float v, unsigned& h, unsigned& m, unsigned& l) {
  unsigned u = __float_as_uint(v);
  h = u & 0xFFFF0000u;
  float r1 = v - __uint_as_float(h);
  m = __float_as_uint(r1) & 0xFFFF0000u;
  float r2 = r1 - __uint_as_float(m);
  l = __float_as_uint(r2);
}

__device__ __forceinline__ void pack2(float e0, float e1,
                                      unsigned& dh, unsigned& dm, unsigned& dl) {
  unsigned h0, m0, l0, h1, m1, l1;
  split3(e0, h0, m0, l0);
  split3(e1, h1, m1, l1);
  dh = (h0 >> 16) | h1;
  dm = (m0 >> 16) | m1;
  dl = (l0 >> 16) | (l1 & 0xFFFF0000u);
}

union FragU { short8 s; unsigned u[4]; };

// ---------------------------------------------------------------------------
// Prep: S_e, inv_norm_e into ws; p 3-limb bf16 into g_B (chunk-major).
// block e: thread t owns k in [8t, 8t+8): gc = t>>2, octet o = t&3.
// ---------------------------------------------------------------------------
__global__ __launch_bounds__(256) void proto_prep(const float* __restrict__ p,
                                                  float* __restrict__ ws) {
  const int e = blockIdx.x, t = threadIdx.x;
  const float* row = p + (size_t)e * kD;
  float4 v0 = *(const float4*)(row + 8 * t);
  float4 v1 = *(const float4*)(row + 8 * t + 4);

  unsigned dh[4], dm[4], dl[4];
  pack2(v0.x, v0.y, dh[0], dm[0], dl[0]);
  pack2(v0.z, v0.w, dh[1], dm[1], dl[1]);
  pack2(v1.x, v1.y, dh[2], dm[2], dl[2]);
  pack2(v1.z, v1.w, dh[3], dm[3], dl[3]);
  const int gc = t >> 2, o = t & 3;
  const int Lr = 16 * o + (e & 15);
  size_t cb = (size_t)((gc * 4 + (e >> 4)) * 3) * 512 + Lr * 8;
  *(uint4*)&g_B[cb]        = make_uint4(dh[0], dh[1], dh[2], dh[3]);   // plane h
  *(uint4*)&g_B[cb + 512]  = make_uint4(dm[0], dm[1], dm[2], dm[3]);   // plane m
  *(uint4*)&g_B[cb + 1024] = make_uint4(dl[0], dl[1], dl[2], dl[3]);   // plane l

  float s = (v0.x + v0.y) + (v0.z + v0.w) + (v1.x + v1.y) + (v1.z + v1.w);
  float q = v0.x*v0.x + v0.y*v0.y + v0.z*v0.z + v0.w*v0.w
          + v1.x*v1.x + v1.y*v1.y + v1.z*v1.z + v1.w*v1.w;
  #pragma unroll
  for (int off = 32; off >= 1; off >>= 1) {
    s += __shfl_xor(s, off, 64);
    q += __shfl_xor(q, off, 64);
  }
  __shared__ float as[4], aq[4];
  if ((t & 63) == 0) { as[t >> 6] = s; aq[t >> 6] = q; }
  __syncthreads();
  if (t == 0) {
    float S = (as[0] + as[1]) + (as[2] + as[3]);
    float Q = (aq[0] + aq[1]) + (aq[2] + aq[3]);
    ws[e]      = S;
    ws[kE + e] = 1.f / fmaxf(sqrtf(Q), 1e-8f);
  }
}

// ---------------------------------------------------------------------------
// Main: one wave per block; wave-private 32 tokens x ALL 64 experts, full K.
// A direct from global x in MFMA layout (2 tiles), 3-limb packed in-register
// (no redundancy); B streamed chunk-major from L2-hot g_B (double-buffered).
// Zero LDS, zero barriers. In-register shfl top-2 epilogue.
// ---------------------------------------------------------------------------
__global__ __launch_bounds__(64, 2) void router_main(
    const float* __restrict__ x, const float* __restrict__ ws,
    float* __restrict__ out_w, float* __restrict__ out_i) {
  const int L    = threadIdx.x;
  const int ln15 = L & 15;
  const int q    = L >> 4;
  const int tok0 = blockIdx.x * kTPW;

  // A-frag sources: tile0 token tok0+ln15, tile1 token tok0+16+ln15; k=gc*32+q*8+j
  const float* xa0 = x + (size_t)(tok0 + ln15) * kD + q * 8;
  const float* xa1 = xa0 + (size_t)16 * kD;
  const unsigned short* bb = g_B + L * 8;

  f32x4 acc[2][4];
  #pragma unroll
  for (int tt = 0; tt < 2; ++tt)
    #pragma unroll
    for (int g = 0; g < 4; ++g) acc[tt][g] = (f32x4){0.f, 0.f, 0.f, 0.f};
  float sx0 = 0.f, sxx0 = 0.f, sx1 = 0.f, sxx1 = 0.f;

  // register pipelines: x depth-2 (4 loads/chunk), B double-buffer depth-1
  float4 xv[2][4];
  short8 bv[2][12];
  #pragma unroll
  for (int c = 0; c < 2; ++c) {
    xv[c][0] = *(const float4*)(xa0 + c * 32);
    xv[c][1] = *(const float4*)(xa0 + c * 32 + 4);
    xv[c][2] = *(const float4*)(xa1 + c * 32);
    xv[c][3] = *(const float4*)(xa1 + c * 32 + 4);
  }
  #pragma unroll
  for (int gp = 0; gp < 12; ++gp) bv[0][gp] = *(const short8*)(bb + gp * 512);

  #pragma unroll 2
  for (int gc = 0; gc < kGC; ++gc) {
    const int cur = gc & 1;
    float4 a00 = xv[cur][0], a01 = xv[cur][1];
    float4 a10 = xv[cur][2], a11 = xv[cur][3];
    if (gc + 2 < kGC) {                       // x prefetch, depth 2 (HBM)
      xv[cur][0] = *(const float4*)(xa0 + (gc + 2) * 32);
      xv[cur][1] = *(const float4*)(xa0 + (gc + 2) * 32 + 4);
      xv[cur][2] = *(const float4*)(xa1 + (gc + 2) * 32);
      xv[cur][3] = *(const float4*)(xa1 + (gc + 2) * 32 + 4);
    }
    if (gc + 1 < kGC) {                       // B prefetch, depth 1 (L2 stream)
      const unsigned short* nb = bb + (size_t)(gc + 1) * 6144;
      #pragma unroll
      for (int gp = 0; gp < 12; ++gp) bv[cur ^ 1][gp] = *(const short8*)(nb + gp * 512);
    }
    // LN stats partials (lane's tokens, its k-slice)
    sx0 += (a00.x + a00.y) + (a00.z + a00.w) + (a01.x + a01.y) + (a01.z + a01.w);
    sxx0 = fmaf(a00.x, a00.x, fmaf(a00.y, a00.y, fmaf(a00.z, a00.z, fmaf(a00.w, a00.w, sxx0))));
    sxx0 = fmaf(a01.x, a01.x, fmaf(a01.y, a01.y, fmaf(a01.z, a01.z, fmaf(a01.w, a01.w, sxx0))));
    sx1 += (a10.x + a10.y) + (a10.z + a10.w) + (a11.x + a11.y) + (a11.z + a11.w);
    sxx1 = fmaf(a10.x, a10.x, fmaf(a10.y, a10.y, fmaf(a10.z, a10.z, fmaf(a10.w, a10.w, sxx1))));
    sxx1 = fmaf(a11.x, a11.x, fmaf(a11.y, a11.y, fmaf(a11.z, a11.z, fmaf(a11.w, a11.w, sxx1))));
    // 3-limb A packs, once per token (wave-private)
    FragU ah0, am0, al0, ah1, am1, al1;
    pack2(a00.x, a00.y, ah0.u[0], am0.u[0], al0.u[0]);
    pack2(a00.z, a00.w, ah0.u[1], am0.u[1], al0.u[1]);
    pack2(a01.x, a01.y, ah0.u[2], am0.u[2], al0.u[2]);
    pack2(a01.z, a01.w, ah0.u[3], am0.u[3], al0.u[3]);
    pack2(a10.x, a10.y, ah1.u[0], am1.u[0], al1.u[0]);
    pack2(a10.z, a10.w, ah1.u[1], am1.u[1], al1.u[1]);
    pack2(a11.x, a11.y, ah1.u[2], am1.u[2], al1.u[2]);
    pack2(a11.z, a11.w, ah1.u[3], am1.u[3], al1.u[3]);
    #pragma unroll
    for (int g = 0; g < 4; ++g) {
      short8 bh = bv[cur][g * 3], bm = bv[cur][g * 3 + 1], bl = bv[cur][g * 3 + 2];
      // 6 limb products per tile: hh, hm, mh, mm, hl, lh
      acc[0][g] = __builtin_amdgcn_mfma_f32_16x16x32_bf16(ah0.s, bh, acc[0][g], 0, 0, 0);
      acc[1][g] = __builtin_amdgcn_mfma_f32_16x16x32_bf16(ah1.s, bh, acc[1][g], 0, 0, 0);
      acc[0][g] = __builtin_amdgcn_mfma_f32_16x16x32_bf16(ah0.s, bm, acc[0][g], 0, 0, 0);
      acc[1][g] = __builtin_amdgcn_mfma_f32_16x16x32_bf16(ah1.s, bm, acc[1][g], 0, 0, 0);
      acc[0][g] = __builtin_amdgcn_mfma_f32_16x16x32_bf16(am0.s, bh, acc[0][g], 0, 0, 0);
      acc[1][g] = __builtin_amdgcn_mfma_f32_16x16x32_bf16(am1.s, bh, acc[1][g], 0, 0, 0);
      acc[0][g] = __builtin_amdgcn_mfma_f32_16x16x32_bf16(am0.s, bm, acc[0][g], 0, 0, 0);
      acc[1][g] = __builtin_amdgcn_mfma_f32_16x16x32_bf16(am1.s, bm, acc[1][g], 0, 0, 0);
      acc[0][g] = __builtin_amdgcn_mfma_f32_16x16x32_bf16(ah0.s, bl, acc[0][g], 0, 0, 0);
      acc[1][g] = __builtin_amdgcn_mfma_f32_16x16x32_bf16(ah1.s, bl, acc[1][g], 0, 0, 0);
      acc[0][g] = __builtin_amdgcn_mfma_f32_16x16x32_bf16(al0.s, bh, acc[0][g], 0, 0, 0);
      acc[1][g] = __builtin_amdgcn_mfma_f32_16x16x32_bf16(al1.s, bh, acc[1][g], 0, 0, 0);
    }
  }

  // stats: q-group {L, L^16, L^32, L^48} covers token ln15 (+16) fully
  sx0  += __shfl_xor(sx0, 16, 64);  sx0  += __shfl_xor(sx0, 32, 64);
  sxx0 += __shfl_xor(sxx0, 16, 64); sxx0 += __shfl_xor(sxx0, 32, 64);
  sx1  += __shfl_xor(sx1, 16, 64);  sx1  += __shfl_xor(sx1, 32, 64);
  sxx1 += __shfl_xor(sxx1, 16, 64); sxx1 += __shfl_xor(sxx1, 32, 64);

  float Se[4], Iv[4];
  #pragma unroll
  for (int g = 0; g < 4; ++g) {
    Se[g] = ws[g * 16 + ln15];
    Iv[g] = ws[kE + g * 16 + ln15];
  }

  // epilogue: token t = tau*16 + q*4 + i; its 64 logits live in the 16 lanes
  // of quad q (4 acc groups each). stats(token r) held by lane r -> bpermute.
  #pragma unroll
  for (int tau = 0; tau < 2; ++tau) {
    float SX = tau ? sx1 : sx0, SQ = tau ? sxx1 : sxx0;
    #pragma unroll
    for (int i = 0; i < 4; ++i) {
      int r = q * 4 + i;
      float mu   = __shfl(SX, r, 64) * (1.f / kD);
      float var  = __shfl(SQ, r, 64) * (1.f / kD) - mu * mu;
      float rstd = rsqrtf(var + 1e-5f);
      float lg[4];
      #pragma unroll
      for (int g = 0; g < 4; ++g)
        lg[g] = (acc[tau][g][i] - mu * Se[g]) * rstd * Iv[g] * 0.125f;

      // local top1 over g ascending (strict > keeps lowest index on ties)
      float v1 = lg[0]; int e1 = ln15;
      #pragma unroll
      for (int g = 1; g < 4; ++g)
        if (lg[g] > v1) { v1 = lg[g]; e1 = g * 16 + ln15; }
      // butterfly over the 16-lane quad group
      #pragma unroll
      for (int off = 8; off >= 1; off >>= 1) {
        float ov = __shfl_xor(v1, off, 64);
        int   oe = __shfl_xor(e1, off, 64);
        if (ov > v1 || (ov == v1 && oe < e1)) { v1 = ov; e1 = oe; }
      }
      // mask winner, second pass
      float m0 = (ln15 == e1 - 0 * 16 && e1 < 16) ? -3.402823466e38f : lg[0];
      float v2; int e2;
      v2 = (e1 == ln15) ? -3.402823466e38f : lg[0]; e2 = ln15;
      #pragma unroll
      for (int g = 1; g < 4; ++g) {
        float c = (e1 == g * 16 + ln15) ? -3.402823466e38f : lg[g];
        if (c > v2) { v2 = c; e2 = g * 16 + ln15; }
      }
      (void)m0;
      #pragma unroll
      for (int off = 8; off >= 1; off >>= 1) {
        float ov = __shfl_xor(v2, off, 64);
        int   oe = __shfl_xor(e2, off, 64);
        if (ov > v2 || (ov == v2 && oe < e2)) { v2 = ov; e2 = oe; }
      }
      if (ln15 == 0) {
        int tg = tok0 + tau * 16 + r;
        float er = expf(v2 - v1);
        float rw = 1.f / (1.f + er);
        out_w[2 * tg]     = rw;
        out_w[2 * tg + 1] = er * rw;
        out_i[2 * tg]     = (float)e1;   // harness reads whole buffer as f32
        out_i[2 * tg + 1] = (float)e2;
      }
    }
  }
}

extern "C" void kernel_launch(void* const* d_in, const int* in_sizes, int n_in,
                              void* d_out, int out_size, void* d_ws, size_t ws_size,
                              hipStream_t stream) {
  const float* x = (const float*)d_in[0];   // [4,4096,2048] fp32
  const float* p = (const float*)d_in[1];   // [64,2048] fp32
  float* ws = (float*)d_ws;                 // 128 floats
  const int T = in_sizes[0] / kD;           // 16384 tokens
  float* out_w = (float*)d_out;
  float* out_i = (float*)d_out + (size_t)T * 2;

  proto_prep<<<kE, 256, 0, stream>>>(p, ws);
  router_main<<<T / kTPW, 64, 0, stream>>>(x, ws, out_w, out_i);
}